// Round 2
// baseline (432.930 us; speedup 1.0000x reference)
//
#include <hip/hip_runtime.h>

#define WIDTH 1024
#define BW 64
#define NB 16
#define ROWS 8
#define HPAD 68                       // 64 + 4 pad: 4 h-groups land on disjoint bank quads
#define ROWSTRIDE (NB * HPAD)         // 1088 floats per staged row

__global__ __launch_bounds__(512, 6)
void griffin_gate_kernel(const float* __restrict__ x,
                         const float* __restrict__ ln_scale,
                         const float* __restrict__ ln_bias,
                         const float* __restrict__ w,
                         const float* __restrict__ b,
                         const float* __restrict__ a_param,
                         float* __restrict__ alpha_out,
                         float* __restrict__ beta_out)
{
    __shared__ float xn_s[ROWS * ROWSTRIDE];   // 34816 B -> LDS allows 4 blocks/CU

    const int t    = threadIdx.x;
    const int wave = t >> 6;
    const int lane = t & 63;
    const long long row_base = (long long)blockIdx.x * ROWS;

    // ---------- Phase-2/3 per-thread constants, loaded BEFORE the barrier ----------
    // (independent of LDS; overlaps L2 latency with phase-1 work)
    const int h   = t >> 5;            // block 0..15 (32 threads per block)
    const int jl  = (t & 31) * 2;      // 2 output cols per thread
    const int col = h * BW + jl;       // == 2*t
    const float2 bias2 = *(const float2*)(b + col);
    const float2 ap    = *(const float2*)(a_param + col);
    float2 sp;                          // softplus(a_param), a_param in [-6.9,-2.2]
    sp.x = log1pf(__expf(ap.x));
    sp.y = log1pf(__expf(ap.y));

    // ---------- Phase 1: LayerNorm. Each wave owns exactly one row. ----------
    {
        const float* xrow = x + (row_base + wave) * WIDTH;
        float4 v[4];
        float s = 0.f, s2 = 0.f;
#pragma unroll
        for (int k = 0; k < 4; ++k) {
            v[k] = *(const float4*)(xrow + 256 * k + 4 * lane);   // coalesced 16B/lane
            s += v[k].x + v[k].y + v[k].z + v[k].w;
            s2 = fmaf(v[k].x, v[k].x, s2);
            s2 = fmaf(v[k].y, v[k].y, s2);
            s2 = fmaf(v[k].z, v[k].z, s2);
            s2 = fmaf(v[k].w, v[k].w, s2);
        }
#pragma unroll
        for (int off = 32; off >= 1; off >>= 1) {
            s  += __shfl_xor(s,  off, 64);
            s2 += __shfl_xor(s2, off, 64);
        }
        const float mean = s * (1.0f / WIDTH);
        const float var  = fmaxf(s2 * (1.0f / WIDTH) - mean * mean, 0.0f);
        const float rstd = rsqrtf(var + 1e-6f);
#pragma unroll
        for (int k = 0; k < 4; ++k) {
            const float4 sc = *(const float4*)(ln_scale + 256 * k + 4 * lane);
            const float4 bi = *(const float4*)(ln_bias  + 256 * k + 4 * lane);
            float4 xn;
            xn.x = fmaf((v[k].x - mean) * rstd, sc.x, bi.x);
            xn.y = fmaf((v[k].y - mean) * rstd, sc.y, bi.y);
            xn.z = fmaf((v[k].z - mean) * rstd, sc.z, bi.z);
            xn.w = fmaf((v[k].w - mean) * rstd, sc.w, bi.w);
            const int hh    = 4 * k + (lane >> 4);
            const int inner = 4 * (lane & 15);
            *(float4*)(&xn_s[wave * ROWSTRIDE + hh * HPAD + inner]) = xn;
        }
    }
    __syncthreads();

    // ---------- Phase 2: block-diagonal matmul. Thread t -> cols [col, col+1], all 8 rows. ----------
    float2 acc[ROWS];
#pragma unroll
    for (int r = 0; r < ROWS; ++r) acc[r] = bias2;

    const float* wh = w + h * (BW * BW) + jl;      // w[h][i][jl..jl+1], L1/L2-resident
    const float* xs = xn_s + h * HPAD;
#pragma unroll 4
    for (int i4 = 0; i4 < 16; ++i4) {
        const float* wp = wh + i4 * 4 * BW;
        const float2 w0 = *(const float2*)(wp);
        const float2 w1 = *(const float2*)(wp + BW);
        const float2 w2 = *(const float2*)(wp + 2 * BW);
        const float2 w3 = *(const float2*)(wp + 3 * BW);
#pragma unroll
        for (int r = 0; r < ROWS; ++r) {
            // 32-lane broadcast; the wave's 2 h-groups sit 68 floats apart -> disjoint bank quads
            const float4 xq = *(const float4*)(xs + r * ROWSTRIDE + i4 * 4);
            acc[r].x = fmaf(xq.x, w0.x, acc[r].x);
            acc[r].y = fmaf(xq.x, w0.y, acc[r].y);
            acc[r].x = fmaf(xq.y, w1.x, acc[r].x);
            acc[r].y = fmaf(xq.y, w1.y, acc[r].y);
            acc[r].x = fmaf(xq.z, w2.x, acc[r].x);
            acc[r].y = fmaf(xq.z, w2.y, acc[r].y);
            acc[r].x = fmaf(xq.w, w3.x, acc[r].x);
            acc[r].y = fmaf(xq.w, w3.y, acc[r].y);
        }
    }

    // ---------- Phase 3: gate chain + store ----------
    float* aout = alpha_out + row_base * WIDTH + col;
    float* bout = beta_out  + row_base * WIDTH + col;
#pragma unroll
    for (int r = 0; r < ROWS; ++r) {
        const float2 g = acc[r];
        float2 al;
        al.x = __expf(-8.0f * sp.x * __builtin_amdgcn_rcpf(1.0f + __expf(-g.x)));
        al.y = __expf(-8.0f * sp.y * __builtin_amdgcn_rcpf(1.0f + __expf(-g.y)));
        al.x = fminf(fmaxf(al.x, 0.05f), 0.95f);
        al.y = fminf(fmaxf(al.y, 0.05f), 0.95f);
        const float2 be = make_float2(1.0f - al.x, 1.0f - al.y);
        *(float2*)(aout + (long long)r * WIDTH) = al;
        *(float2*)(bout + (long long)r * WIDTH) = be;
    }
}

extern "C" void kernel_launch(void* const* d_in, const int* in_sizes, int n_in,
                              void* d_out, int out_size, void* d_ws, size_t ws_size,
                              hipStream_t stream)
{
    const float* x        = (const float*)d_in[0];
    const float* ln_scale = (const float*)d_in[1];
    const float* ln_bias  = (const float*)d_in[2];
    const float* w        = (const float*)d_in[3];
    const float* b        = (const float*)d_in[4];
    const float* a_param  = (const float*)d_in[5];

    const long long total = (long long)in_sizes[0];        // 4*8192*1024
    const long long rows  = total / WIDTH;                 // 32768
    float* alpha_out = (float*)d_out;
    float* beta_out  = alpha_out + total;

    const int grid = (int)(rows / ROWS);                   // 4096
    griffin_gate_kernel<<<grid, 512, 0, stream>>>(x, ln_scale, ln_bias, w, b, a_param,
                                                  alpha_out, beta_out);
}

// Round 3
// 428.052 us; speedup vs baseline: 1.0114x; 1.0114x over previous
//
#include <hip/hip_runtime.h>

#define WIDTH 1024
#define BW 64
#define NB 16
#define ROWS 8
#define HPAD 68                       // 64 + 4 pad: 4 h-groups land on disjoint bank quads
#define ROWSTRIDE (NB * HPAD)         // 1088 floats per staged row

__global__ __launch_bounds__(512, 8)
void griffin_gate_kernel(const float* __restrict__ x,
                         const float* __restrict__ ln_scale,
                         const float* __restrict__ ln_bias,
                         const float* __restrict__ w,
                         const float* __restrict__ b,
                         const float* __restrict__ a_param,
                         float* __restrict__ alpha_out,
                         float* __restrict__ beta_out)
{
    __shared__ float xn_s[ROWS * ROWSTRIDE];   // 34816 B -> 4 blocks/CU

    const int t    = threadIdx.x;
    const int wave = t >> 6;
    const int lane = t & 63;
    const long long row_base = (long long)blockIdx.x * ROWS;

    // ---------- Phase 1: LayerNorm. Each wave owns exactly one row. ----------
    {
        const float* xrow = x + (row_base + wave) * WIDTH;
        float4 v[4];
        float s = 0.f, s2 = 0.f;
#pragma unroll
        for (int k = 0; k < 4; ++k) {
            v[k] = *(const float4*)(xrow + 256 * k + 4 * lane);   // coalesced 16B/lane
            s += v[k].x + v[k].y + v[k].z + v[k].w;
            s2 = fmaf(v[k].x, v[k].x, s2);
            s2 = fmaf(v[k].y, v[k].y, s2);
            s2 = fmaf(v[k].z, v[k].z, s2);
            s2 = fmaf(v[k].w, v[k].w, s2);
        }
#pragma unroll
        for (int off = 32; off >= 1; off >>= 1) {
            s  += __shfl_xor(s,  off, 64);
            s2 += __shfl_xor(s2, off, 64);
        }
        const float mean = s * (1.0f / WIDTH);
        const float var  = fmaxf(s2 * (1.0f / WIDTH) - mean * mean, 0.0f);
        const float rstd = rsqrtf(var + 1e-6f);
#pragma unroll
        for (int k = 0; k < 4; ++k) {
            const float4 sc = *(const float4*)(ln_scale + 256 * k + 4 * lane);
            const float4 bi = *(const float4*)(ln_bias  + 256 * k + 4 * lane);
            float4 xn;
            xn.x = fmaf((v[k].x - mean) * rstd, sc.x, bi.x);
            xn.y = fmaf((v[k].y - mean) * rstd, sc.y, bi.y);
            xn.z = fmaf((v[k].z - mean) * rstd, sc.z, bi.z);
            xn.w = fmaf((v[k].w - mean) * rstd, sc.w, bi.w);
            const int hh    = 4 * k + (lane >> 4);
            const int inner = 4 * (lane & 15);
            *(float4*)(&xn_s[wave * ROWSTRIDE + hh * HPAD + inner]) = xn;
        }
    }
    __syncthreads();

    // ---------- Phase 2: block-diag matmul. Thread -> 4 cols x 4 rows. ----------
    // threads 0..255: rows 0..3;  256..511: rows 4..7
    const int rg  = t >> 8;                 // row-group
    const int h   = (t & 255) >> 4;         // which 64-wide block
    const int jq  = t & 15;                 // col quad within block
    const int col = h * BW + jq * 4;

    float4 acc[4];
#pragma unroll
    for (int r = 0; r < 4; ++r) acc[r] = make_float4(0.f, 0.f, 0.f, 0.f);

    const float* wh = w + h * (BW * BW) + jq * 4;       // w[h][i][4jq..], L1/L2-resident
    const float* xs = xn_s + (rg * 4) * ROWSTRIDE + h * HPAD;

#pragma unroll 4
    for (int i4 = 0; i4 < 16; ++i4) {
        // xq[r]: 16-lane broadcast, 4 h-groups on disjoint bank quads
        float4 xq0 = *(const float4*)(xs + 0 * ROWSTRIDE + i4 * 4);
        float4 xq1 = *(const float4*)(xs + 1 * ROWSTRIDE + i4 * 4);
        float4 xq2 = *(const float4*)(xs + 2 * ROWSTRIDE + i4 * 4);
        float4 xq3 = *(const float4*)(xs + 3 * ROWSTRIDE + i4 * 4);
        const float* wp = wh + i4 * 4 * BW;
#pragma unroll
        for (int s = 0; s < 4; ++s) {
            const float4 ws = *(const float4*)(wp + s * BW);
            const float  x0 = (&xq0.x)[s], x1 = (&xq1.x)[s], x2 = (&xq2.x)[s], x3 = (&xq3.x)[s];
            acc[0].x = fmaf(x0, ws.x, acc[0].x); acc[0].y = fmaf(x0, ws.y, acc[0].y);
            acc[0].z = fmaf(x0, ws.z, acc[0].z); acc[0].w = fmaf(x0, ws.w, acc[0].w);
            acc[1].x = fmaf(x1, ws.x, acc[1].x); acc[1].y = fmaf(x1, ws.y, acc[1].y);
            acc[1].z = fmaf(x1, ws.z, acc[1].z); acc[1].w = fmaf(x1, ws.w, acc[1].w);
            acc[2].x = fmaf(x2, ws.x, acc[2].x); acc[2].y = fmaf(x2, ws.y, acc[2].y);
            acc[2].z = fmaf(x2, ws.z, acc[2].z); acc[2].w = fmaf(x2, ws.w, acc[2].w);
            acc[3].x = fmaf(x3, ws.x, acc[3].x); acc[3].y = fmaf(x3, ws.y, acc[3].y);
            acc[3].z = fmaf(x3, ws.z, acc[3].z); acc[3].w = fmaf(x3, ws.w, acc[3].w);
        }
    }

    // ---------- Phase 3: bias + gate chain + store ----------
    const float4 bias4 = *(const float4*)(b + col);
    const float4 ap    = *(const float4*)(a_param + col);
    float4 sp;   // softplus(a_param); a_param in [-6.9,-2.2] so expf safe
    sp.x = log1pf(__expf(ap.x));
    sp.y = log1pf(__expf(ap.y));
    sp.z = log1pf(__expf(ap.z));
    sp.w = log1pf(__expf(ap.w));

    float* aout = alpha_out + (row_base + rg * 4) * WIDTH + col;
    float* bout = beta_out  + (row_base + rg * 4) * WIDTH + col;
#pragma unroll
    for (int r = 0; r < 4; ++r) {
        float4 g;
        g.x = acc[r].x + bias4.x;
        g.y = acc[r].y + bias4.y;
        g.z = acc[r].z + bias4.z;
        g.w = acc[r].w + bias4.w;
        float4 al;
        al.x = __expf(-8.0f * sp.x * __builtin_amdgcn_rcpf(1.0f + __expf(-g.x)));
        al.y = __expf(-8.0f * sp.y * __builtin_amdgcn_rcpf(1.0f + __expf(-g.y)));
        al.z = __expf(-8.0f * sp.z * __builtin_amdgcn_rcpf(1.0f + __expf(-g.z)));
        al.w = __expf(-8.0f * sp.w * __builtin_amdgcn_rcpf(1.0f + __expf(-g.w)));
        al.x = fminf(fmaxf(al.x, 0.05f), 0.95f);
        al.y = fminf(fmaxf(al.y, 0.05f), 0.95f);
        al.z = fminf(fmaxf(al.z, 0.05f), 0.95f);
        al.w = fminf(fmaxf(al.w, 0.05f), 0.95f);
        const float4 be = make_float4(1.0f - al.x, 1.0f - al.y, 1.0f - al.z, 1.0f - al.w);
        *(float4*)(aout + (long long)r * WIDTH) = al;
        *(float4*)(bout + (long long)r * WIDTH) = be;
    }
}

extern "C" void kernel_launch(void* const* d_in, const int* in_sizes, int n_in,
                              void* d_out, int out_size, void* d_ws, size_t ws_size,
                              hipStream_t stream)
{
    const float* x        = (const float*)d_in[0];
    const float* ln_scale = (const float*)d_in[1];
    const float* ln_bias  = (const float*)d_in[2];
    const float* w        = (const float*)d_in[3];
    const float* b        = (const float*)d_in[4];
    const float* a_param  = (const float*)d_in[5];

    const long long total = (long long)in_sizes[0];        // 4*8192*1024
    const long long rows  = total / WIDTH;                 // 32768
    float* alpha_out = (float*)d_out;
    float* beta_out  = alpha_out + total;

    const int grid = (int)(rows / ROWS);                   // 4096
    griffin_gate_kernel<<<grid, 512, 0, stream>>>(x, ln_scale, ln_bias, w, b, a_param,
                                                  alpha_out, beta_out);
}

// Round 4
// 415.144 us; speedup vs baseline: 1.0428x; 1.0311x over previous
//
#include <hip/hip_runtime.h>
#include <hip/hip_bf16.h>

#define WIDTH 1024
#define BW 64
#define NB 16
#define ROWS 16          // tokens per workgroup

typedef __attribute__((ext_vector_type(8))) __bf16 bf16x8;
typedef __attribute__((ext_vector_type(4))) float f32x4;
typedef __attribute__((ext_vector_type(4))) unsigned short u16x4;
typedef __attribute__((ext_vector_type(8))) unsigned short u16x8;

__device__ __forceinline__ unsigned short f2bf(float f) {
    __hip_bfloat16 h = __float2bfloat16(f);   // RNE
    return __builtin_bit_cast(unsigned short, h);
}

// ---------- prep: w (fp32 [16][64][64]) -> bf16 in per-lane MFMA A-fragment order;
// ---------- msp[j] = -8 * softplus(a_param[j])
// Fragment block (h, m, s) = 64 lanes x 16 B; lane l, elem e holds
// A[row = l&15][k = (l>>4)*8 + e] of the wT tile = w[h][i = s*32 + (l>>4)*8 + e][j = m*16 + (l&15)]
__global__ void prep_kernel(const float* __restrict__ w, const float* __restrict__ a_param,
                            unsigned short* __restrict__ wbf, float* __restrict__ msp) {
    const int tid = blockIdx.x * 256 + threadIdx.x;       // 8192 threads
    const int h = tid >> 9, m = (tid >> 7) & 3, s = (tid >> 6) & 1, l = tid & 63;
    const int j  = m * 16 + (l & 15);
    const int i0 = s * 32 + ((l >> 4) << 3);
    const float* wp = w + h * (BW * BW) + i0 * BW + j;
    u16x8 o;
#pragma unroll
    for (int e = 0; e < 8; ++e) o[e] = f2bf(wp[e * BW]);
    *(u16x8*)(wbf + (long long)tid * 8) = o;
    if (tid < WIDTH) {
        msp[tid] = -8.0f * log1pf(__expf(a_param[tid]));
    }
}

__global__ __launch_bounds__(512, 6)
void griffin_gate_kernel(const float* __restrict__ x,
                         const float* __restrict__ ln_scale,
                         const float* __restrict__ ln_bias,
                         const float* __restrict__ b,
                         const unsigned short* __restrict__ wbf,
                         const float* __restrict__ msp,
                         float* __restrict__ alpha_out,
                         float* __restrict__ beta_out)
{
    __shared__ unsigned short xn_s[ROWS * WIDTH];   // 32 KiB, bf16, XOR-swizzled rows

    const int t  = threadIdx.x;
    const int wv = t >> 6;
    const int l  = t & 63;
    const long long base = (long long)blockIdx.x * ROWS;

    // ---------- Phase 1: LayerNorm, 2 rows per wave, write bf16 to LDS ----------
#pragma unroll
    for (int rr = 0; rr < 2; ++rr) {
        const int tok = wv * 2 + rr;
        const float* xrow = x + (base + tok) * WIDTH;
        float4 v[4];
        float s = 0.f, s2 = 0.f;
#pragma unroll
        for (int c = 0; c < 4; ++c) {
            v[c] = *(const float4*)(xrow + 256 * c + 4 * l);   // coalesced 16B/lane
            s += v[c].x + v[c].y + v[c].z + v[c].w;
            s2 = fmaf(v[c].x, v[c].x, s2);
            s2 = fmaf(v[c].y, v[c].y, s2);
            s2 = fmaf(v[c].z, v[c].z, s2);
            s2 = fmaf(v[c].w, v[c].w, s2);
        }
#pragma unroll
        for (int off = 32; off >= 1; off >>= 1) {
            s  += __shfl_xor(s,  off, 64);
            s2 += __shfl_xor(s2, off, 64);
        }
        const float mean = s * (1.0f / WIDTH);
        const float var  = fmaxf(s2 * (1.0f / WIDTH) - mean * mean, 0.0f);
        const float rstd = rsqrtf(var + 1e-6f);
        char* rowp = (char*)(xn_s + tok * WIDTH);
        const int swz = (tok & 7) << 4;
#pragma unroll
        for (int c = 0; c < 4; ++c) {
            const float4 sc = *(const float4*)(ln_scale + 256 * c + 4 * l);
            const float4 bi = *(const float4*)(ln_bias  + 256 * c + 4 * l);
            u16x4 p;
            p[0] = f2bf(fmaf((v[c].x - mean) * rstd, sc.x, bi.x));
            p[1] = f2bf(fmaf((v[c].y - mean) * rstd, sc.y, bi.y));
            p[2] = f2bf(fmaf((v[c].z - mean) * rstd, sc.z, bi.z));
            p[3] = f2bf(fmaf((v[c].w - mean) * rstd, sc.w, bi.w));
            // pre-swizzle byte offset: bf16 col k lives at byte (2k)^swz within the row
            *(u16x4*)(rowp + ((512 * c + 8 * l) ^ swz)) = p;
        }
    }
    __syncthreads();

    // ---------- Phase 2+3: MFMA (swapped: C'[j][token]) + gate epilogue ----------
    const int tokc = l & 15;          // C col = token  (verified m89 layout)
    const int g    = l >> 4;          // C row group: j-local = 4*g + reg
    const char* xb   = (const char*)(xn_s + tokc * WIDTH);
    const int   swzr = (tokc & 7) << 4;
    float* aout = alpha_out + (base + tokc) * WIDTH;
    float* bout = beta_out  + (base + tokc) * WIDTH;

#pragma unroll
    for (int hh = 0; hh < 2; ++hh) {
        const int h = wv * 2 + hh;
        // B-fragments (xn^T): lane reads [token][k = h*64 + s*32 + g*8 .. +7]
        const bf16x8 b0 = *(const bf16x8*)(xb + ((h * 128 +  0 + g * 16) ^ swzr));
        const bf16x8 b1 = *(const bf16x8*)(xb + ((h * 128 + 64 + g * 16) ^ swzr));
        // A-fragments (w^T, preconverted): frag (m,s) at wbf[((h*8+m*2+s)*64+l)*8]
        const u16x8* wb = (const u16x8*)wbf + h * 512 + l;

#pragma unroll
        for (int m = 0; m < 4; ++m) {
            f32x4 acc = {0.f, 0.f, 0.f, 0.f};
            acc = __builtin_amdgcn_mfma_f32_16x16x32_bf16(
                      __builtin_bit_cast(bf16x8, wb[(m * 2 + 0) * 64]), b0, acc, 0, 0, 0);
            acc = __builtin_amdgcn_mfma_f32_16x16x32_bf16(
                      __builtin_bit_cast(bf16x8, wb[(m * 2 + 1) * 64]), b1, acc, 0, 0, 0);

            const int jbase = h * 64 + m * 16 + g * 4;
            const float4 bias4 = *(const float4*)(b   + jbase);
            const float4 ms4   = *(const float4*)(msp + jbase);
            float4 al, be;
#pragma unroll
            for (int e = 0; e < 4; ++e) {
                const float gt  = acc[e] + (&bias4.x)[e];
                const float sig = __builtin_amdgcn_rcpf(1.0f + __expf(-gt));
                float a = __expf((&ms4.x)[e] * sig);
                a = fminf(fmaxf(a, 0.05f), 0.95f);
                (&al.x)[e] = a;
                (&be.x)[e] = 1.0f - a;
            }
            *(float4*)(aout + jbase) = al;
            *(float4*)(bout + jbase) = be;
        }
    }
}

extern "C" void kernel_launch(void* const* d_in, const int* in_sizes, int n_in,
                              void* d_out, int out_size, void* d_ws, size_t ws_size,
                              hipStream_t stream)
{
    const float* x        = (const float*)d_in[0];
    const float* ln_scale = (const float*)d_in[1];
    const float* ln_bias  = (const float*)d_in[2];
    const float* w        = (const float*)d_in[3];
    const float* b        = (const float*)d_in[4];
    const float* a_param  = (const float*)d_in[5];

    const long long total = (long long)in_sizes[0];        // 4*8192*1024
    const long long rows  = total / WIDTH;                 // 32768
    float* alpha_out = (float*)d_out;
    float* beta_out  = alpha_out + total;

    unsigned short* wbf = (unsigned short*)d_ws;                       // 131072 B
    float*          msp = (float*)((char*)d_ws + NB * BW * BW * 2);    // 4096 B

    prep_kernel<<<32, 256, 0, stream>>>(w, a_param, wbf, msp);
    const int grid = (int)(rows / ROWS);                   // 2048
    griffin_gate_kernel<<<grid, 512, 0, stream>>>(x, ln_scale, ln_bias, b, wbf, msp,
                                                  alpha_out, beta_out);
}

// Round 6
// 389.759 us; speedup vs baseline: 1.1108x; 1.0651x over previous
//
#include <hip/hip_runtime.h>
#include <hip/hip_bf16.h>

#define WIDTH 1024
#define BW 64
#define NB 16
#define ROWS 16          // tokens per workgroup

typedef __attribute__((ext_vector_type(8))) __bf16 bf16x8;
typedef __attribute__((ext_vector_type(4))) float f32x4;
typedef __attribute__((ext_vector_type(4))) unsigned short u16x4;
typedef __attribute__((ext_vector_type(8))) unsigned short u16x8;

__device__ __forceinline__ unsigned short f2bf(float f) {
    __hip_bfloat16 h = __float2bfloat16(f);   // RNE
    return __builtin_bit_cast(unsigned short, h);
}
__device__ __forceinline__ float bf2f(unsigned short u) {
    unsigned int v = (unsigned int)u << 16;
    return __builtin_bit_cast(float, v);
}

// ---------- prep: w -> bf16 MFMA A-fragments; msp[j] = -8*softplus(a_param[j])
// Fragment block (h, m, s): lane l elem e holds w[h][i = s*32 + (l>>4)*8 + e][j = m*16 + (l&15)]
__global__ void prep_kernel(const float* __restrict__ w, const float* __restrict__ a_param,
                            unsigned short* __restrict__ wbf, float* __restrict__ msp) {
    const int tid = blockIdx.x * 256 + threadIdx.x;       // 8192 threads
    const int h = tid >> 9, m = (tid >> 7) & 3, s = (tid >> 6) & 1, l = tid & 63;
    const int j  = m * 16 + (l & 15);
    const int i0 = s * 32 + ((l >> 4) << 3);
    const float* wp = w + h * (BW * BW) + i0 * BW + j;
    u16x8 o;
#pragma unroll
    for (int e = 0; e < 8; ++e) o[e] = f2bf(wp[e * BW]);
    *(u16x8*)(wbf + (long long)tid * 8) = o;
    if (tid < WIDTH) msp[tid] = -8.0f * log1pf(__expf(a_param[tid]));
}

__global__ __launch_bounds__(512, 6)
void griffin_gate_kernel(const float* __restrict__ x,
                         const float* __restrict__ ln_scale,
                         const float* __restrict__ ln_bias,
                         const float* __restrict__ b,
                         const unsigned short* __restrict__ wbf,
                         const float* __restrict__ msp,
                         float* __restrict__ alpha_out,
                         float* __restrict__ beta_out)
{
    // One 32 KiB buffer, used twice: phase1/2 = xn (bf16, swizzled), phase3 = alpha (bf16, swizzled)
    __shared__ unsigned short smem[ROWS * WIDTH];

    const int t  = threadIdx.x;
    const int wv = t >> 6;
    const int l  = t & 63;
    const long long base = (long long)blockIdx.x * ROWS;

    // ---------- Phase 1: LayerNorm, 2 rows per wave, bf16 to LDS (XOR-swizzled rows) ----------
#pragma unroll
    for (int rr = 0; rr < 2; ++rr) {
        const int tok = wv * 2 + rr;
        const float* xrow = x + (base + tok) * WIDTH;
        float4 v[4];
        float s = 0.f, s2 = 0.f;
#pragma unroll
        for (int c = 0; c < 4; ++c) {
            v[c] = *(const float4*)(xrow + 256 * c + 4 * l);   // coalesced 16B/lane
            s += v[c].x + v[c].y + v[c].z + v[c].w;
            s2 = fmaf(v[c].x, v[c].x, s2);
            s2 = fmaf(v[c].y, v[c].y, s2);
            s2 = fmaf(v[c].z, v[c].z, s2);
            s2 = fmaf(v[c].w, v[c].w, s2);
        }
#pragma unroll
        for (int off = 32; off >= 1; off >>= 1) {
            s  += __shfl_xor(s,  off, 64);
            s2 += __shfl_xor(s2, off, 64);
        }
        const float mean = s * (1.0f / WIDTH);
        const float var  = fmaxf(s2 * (1.0f / WIDTH) - mean * mean, 0.0f);
        const float rstd = rsqrtf(var + 1e-6f);
        char* rowp = (char*)(smem + tok * WIDTH);
        const int swz = (tok & 7) << 4;
#pragma unroll
        for (int c = 0; c < 4; ++c) {
            const float4 sc = *(const float4*)(ln_scale + 256 * c + 4 * l);
            const float4 bi = *(const float4*)(ln_bias  + 256 * c + 4 * l);
            u16x4 p;
            p[0] = f2bf(fmaf((v[c].x - mean) * rstd, sc.x, bi.x));
            p[1] = f2bf(fmaf((v[c].y - mean) * rstd, sc.y, bi.y));
            p[2] = f2bf(fmaf((v[c].z - mean) * rstd, sc.z, bi.z));
            p[3] = f2bf(fmaf((v[c].w - mean) * rstd, sc.w, bi.w));
            *(u16x4*)(rowp + ((512 * c + 8 * l) ^ swz)) = p;
        }
    }
    __syncthreads();

    // ---------- Phase 2a: pull this thread's xn B-fragments (then xn is dead) ----------
    const int tokc = l & 15;          // C col = token  (m89 layout)
    const int g    = l >> 4;          // C row group: j-local = 4*g + e
    const char* xb   = (const char*)(smem + tokc * WIDTH);
    const int   swzr = (tokc & 7) << 4;
    bf16x8 bfrag[2][2];
#pragma unroll
    for (int hh = 0; hh < 2; ++hh) {
        const int h = wv * 2 + hh;
        bfrag[hh][0] = *(const bf16x8*)(xb + ((h * 128 +  0 + g * 16) ^ swzr));
        bfrag[hh][1] = *(const bf16x8*)(xb + ((h * 128 + 64 + g * 16) ^ swzr));
    }
    __syncthreads();   // all xn reads complete; smem reusable for alpha

    // ---------- Phase 2b: MFMA + gate -> alpha bf16 into LDS (swizzled, conflict-free) ----------
    char* arow = (char*)(smem + tokc * WIDTH);
#pragma unroll
    for (int hh = 0; hh < 2; ++hh) {
        const int h = wv * 2 + hh;
        const u16x8* wb = (const u16x8*)wbf + h * 512 + l;
#pragma unroll
        for (int m = 0; m < 4; ++m) {
            const int jb = h * 64 + m * 16 + g * 4;
            const float4 bias4 = *(const float4*)(b + jb);
            f32x4 acc = {bias4.x, bias4.y, bias4.z, bias4.w};
            acc = __builtin_amdgcn_mfma_f32_16x16x32_bf16(
                      __builtin_bit_cast(bf16x8, wb[(m * 2 + 0) * 64]), bfrag[hh][0], acc, 0, 0, 0);
            acc = __builtin_amdgcn_mfma_f32_16x16x32_bf16(
                      __builtin_bit_cast(bf16x8, wb[(m * 2 + 1) * 64]), bfrag[hh][1], acc, 0, 0, 0);
            const float4 ms4 = *(const float4*)(msp + jb);
            u16x4 pk;
#pragma unroll
            for (int e = 0; e < 4; ++e) {
                const float gt  = acc[e];
                const float sig = __builtin_amdgcn_rcpf(1.0f + __expf(-gt));
                float a = __expf((&ms4.x)[e] * sig);
                a = fminf(fmaxf(a, 0.05f), 0.95f);
                pk[e] = f2bf(a);
            }
            // byte offset jb*2 = h*128 + m*32 + g*8, XOR-swizzled: 2-way max (free)
            *(u16x4*)(arow + ((h * 128 + m * 32 + g * 8) ^ swzr)) = pk;
        }
    }
    __syncthreads();

    // ---------- Phase 3: stream alpha/beta out, fully coalesced ----------
#pragma unroll
    for (int rr = 0; rr < 2; ++rr) {
        const int r = wv * 2 + rr;
        const char* rp = (const char*)(smem + r * WIDTH);
        const int sz = (r & 7) << 4;
        float* ag = alpha_out + (base + r) * WIDTH;
        float* bg = beta_out  + (base + r) * WIDTH;
#pragma unroll
        for (int half = 0; half < 2; ++half) {
            const int phys = half * 1024 + 16 * l;          // stride-16B physical: conflict-free
            const u16x8 v = *(const u16x8*)(rp + phys);
            const int c0 = (phys ^ sz) >> 1;                // logical col group (8 cols)
            float4 a0, a1, b0, b1;
            a0.x = bf2f(v[0]); a0.y = bf2f(v[1]); a0.z = bf2f(v[2]); a0.w = bf2f(v[3]);
            a1.x = bf2f(v[4]); a1.y = bf2f(v[5]); a1.z = bf2f(v[6]); a1.w = bf2f(v[7]);
            b0.x = 1.0f - a0.x; b0.y = 1.0f - a0.y; b0.z = 1.0f - a0.z; b0.w = 1.0f - a0.w;
            b1.x = 1.0f - a1.x; b1.y = 1.0f - a1.y; b1.z = 1.0f - a1.z; b1.w = 1.0f - a1.w;
            *(float4*)(ag + c0)     = a0;
            *(float4*)(ag + c0 + 4) = a1;
            *(float4*)(bg + c0)     = b0;
            *(float4*)(bg + c0 + 4) = b1;
        }
    }
}

extern "C" void kernel_launch(void* const* d_in, const int* in_sizes, int n_in,
                              void* d_out, int out_size, void* d_ws, size_t ws_size,
                              hipStream_t stream)
{
    const float* x        = (const float*)d_in[0];
    const float* ln_scale = (const float*)d_in[1];
    const float* ln_bias  = (const float*)d_in[2];
    const float* w        = (const float*)d_in[3];
    const float* b        = (const float*)d_in[4];
    const float* a_param  = (const float*)d_in[5];

    const long long total = (long long)in_sizes[0];        // 4*8192*1024
    const long long rows  = total / WIDTH;                 // 32768
    float* alpha_out = (float*)d_out;
    float* beta_out  = alpha_out + total;

    unsigned short* wbf = (unsigned short*)d_ws;                       // 131072 B
    float*          msp = (float*)((char*)d_ws + NB * BW * BW * 2);    // 4096 B

    prep_kernel<<<32, 256, 0, stream>>>(w, a_param, wbf, msp);
    const int grid = (int)(rows / ROWS);                   // 2048
    griffin_gate_kernel<<<grid, 512, 0, stream>>>(x, ln_scale, ln_bias, b, wbf, msp,
                                                  alpha_out, beta_out);
}